// Round 14
// baseline (236.364 us; speedup 1.0000x reference)
//
#include <hip/hip_runtime.h>
#include <hip/hip_bf16.h>

typedef __hip_bfloat16 bf16;
typedef unsigned short ush;
typedef __attribute__((ext_vector_type(8))) unsigned short ush8;
typedef __attribute__((ext_vector_type(8))) short s8v;     // 8 bf16 for MFMA A/B
typedef __attribute__((ext_vector_type(4))) float f4;

#define IN_CH 32
#define HID 128
#define OUT_CH 32
#define S_CAP 32             // fixed csr slots per node; rank>=S_CAP -> overflow list
#define OVF_CAP 80000        // overflow pair capacity (bench data: ~0 used)
#define NB_MAX 2048          // max buckets (256 nodes each) -> n_nodes <= 524288
#define SC_CHUNK 8192        // edges per block in chunked scatter
// segment invariant: SC_CHUNK/NB ~ 21 records (84B); round-12 lesson: don't shrink both
#define HT_STRIDE 132        // htile row stride (ush): bank = 8*kgrp + col/2 + c -> conflict-free

__device__ __forceinline__ float bf2f(ush u) {
    return __uint_as_float(((unsigned)u) << 16);
}
__device__ __forceinline__ ush f2bf(float f) {
    __hip_bfloat16 b = __float2bfloat16(f);
    return __builtin_bit_cast(ush, b);
}
__device__ __forceinline__ float ldf(const void* __restrict__ p, size_t idx, int isbf16) {
    return isbf16 ? bf2f(((const ush*)p)[idx]) : ((const float*)p)[idx];
}
__device__ __forceinline__ int ld_edge(const int* __restrict__ ei, size_t elem, int wide) {
    return wide ? ei[2 * elem] : ei[elem];
}

// ---------- sniff dtypes: flags[0]=float_is_bf16, flags[1]=edge_is_i64 ----------
__global__ void k_detect(const unsigned short* __restrict__ xraw,
                         const int* __restrict__ ei, int* __restrict__ flags) {
    __shared__ int cnt_exp, any_nz;
    if (threadIdx.x == 0) { cnt_exp = 0; any_nz = 0; }
    __syncthreads();
    int local = 0;
    for (int k = threadIdx.x; k < 4096; k += 256) {
        int e = (xraw[k] >> 7) & 0xFF;
        if (e >= 100 && e <= 140) ++local;
    }
    atomicAdd(&cnt_exp, local);
    for (int k = threadIdx.x; k < 2048; k += 256)
        if (ei[2 * k + 1] != 0) any_nz = 1;   // benign race
    __syncthreads();
    if (threadIdx.x == 0) {
        flags[0] = (cnt_exp > 3500) ? 1 : 0;
        flags[1] = any_nz ? 0 : 1;
    }
}

// ---------- FALLBACK: fused count+place (one global atomic + scattered store per edge) ----------
__global__ void k_fillp(const int* __restrict__ ei, int n_edges,
                        const int* __restrict__ flags,
                        int* __restrict__ cnt, int* __restrict__ csr,
                        int* __restrict__ ovf, int* __restrict__ ovfn) {
    int e = blockIdx.x * blockDim.x + threadIdx.x;
    if (e >= n_edges) return;
    int w = flags[1];
    int d  = ld_edge(ei, (size_t)n_edges + e, w);
    int sc = ld_edge(ei, (size_t)e, w);
    int r = atomicAdd(&cnt[d], 1);
    if (r < S_CAP) {
        csr[d * S_CAP + r] = sc;
    } else {
        int o = atomicAdd(ovfn, 1);
        if (o < OVF_CAP) { ((int2*)ovf)[o] = make_int2(d, sc); }
    }
}

// ---------- bucketed partition: hist -> scan -> chunked scatter -> build(LDS) ----------
// bucket b = dst >> 8 (256 nodes/bucket); packed record = src | (dst&255)<<24

__global__ __launch_bounds__(256) void k_hist(
        const int* __restrict__ ei, int n_edges,
        const int* __restrict__ flags,
        int* __restrict__ hist, int NB) {
    __shared__ int hl[NB_MAX];   // 8 KB
    int t = threadIdx.x;
    for (int k = t; k < NB; k += 256) hl[k] = 0;
    __syncthreads();
    int w = flags[1];
    int stride = gridDim.x * 256;
    for (int e = blockIdx.x * 256 + t; e < n_edges; e += stride) {
        int d = ld_edge(ei, (size_t)n_edges + e, w);
        atomicAdd(&hl[d >> 8], 1);
    }
    __syncthreads();
    for (int k = t; k < NB; k += 256)
        if (hl[k]) atomicAdd(&hist[k], hl[k]);
}

// single block; exclusive prefix over NB buckets; cursor[b]=base[b]
__global__ __launch_bounds__(256) void k_scan(
        const int* __restrict__ hist,
        int* __restrict__ base, int* __restrict__ cursor, int NB) {
    __shared__ int part[256];
    int t = threadIdx.x;
    int chunk = (NB + 255) / 256;
    int lo = t * chunk, hi = min(NB, (t + 1) * chunk);
    int s = 0;
    for (int k = lo; k < hi; ++k) s += hist[k];
    part[t] = s;
    __syncthreads();
    if (t == 0) {
        int r = 0;
        for (int q = 0; q < 256; ++q) { int v = part[q]; part[q] = r; r += v; }
        base[NB] = r;
    }
    __syncthreads();
    int r = part[t];
    for (int k = lo; k < hi; ++k) {
        base[k] = r; cursor[k] = r;
        r += hist[k];
    }
}

// chunked two-pass scatter: per (block,bucket) ONE global atomic reservation,
// then contiguous segment writes (fills lines -> no 64B/record amplification).
__global__ __launch_bounds__(256) void k_scatter(
        const int* __restrict__ ei, int n_edges,
        const int* __restrict__ flags,
        int* __restrict__ cursor, int* __restrict__ pairs, int NB) {
    __shared__ int cA[NB_MAX];   // pass A: chunk histogram; pass B: rank counter
    __shared__ int oA[NB_MAX];   // reserved global offset per bucket
    int t = threadIdx.x;
    int w = flags[1];
    int e0 = blockIdx.x * SC_CHUNK;
    int ecnt = min(SC_CHUNK, n_edges - e0);
    if (ecnt <= 0) return;
    for (int k = t; k < NB; k += 256) cA[k] = 0;
    __syncthreads();
    // pass A: chunk histogram (LDS atomics)
    for (int k = t; k < ecnt; k += 256) {
        int d = ld_edge(ei, (size_t)n_edges + e0 + k, w);
        atomicAdd(&cA[d >> 8], 1);
    }
    __syncthreads();
    // reserve: one global atomic per non-empty (block,bucket); reset rank counters
    for (int b = t; b < NB; b += 256) {
        int c = cA[b];
        oA[b] = c ? atomicAdd(&cursor[b], c) : 0;
        cA[b] = 0;
    }
    __syncthreads();
    // pass B: place records contiguously within reserved segments
    for (int k = t; k < ecnt; k += 256) {
        int d  = ld_edge(ei, (size_t)n_edges + e0 + k, w);
        int sc = ld_edge(ei, (size_t)e0 + k, w);
        int b = d >> 8;
        int r = atomicAdd(&cA[b], 1);
        pairs[oA[b] + r] = sc | ((d & 255) << 24);
    }
}

// one block per bucket (256 nodes): LDS count+place, coalesced writeout of cnt + csr
__global__ __launch_bounds__(256) void k_build(
        const int* __restrict__ pairs, const int* __restrict__ base,
        int* __restrict__ cnt, int* __restrict__ csr,
        int* __restrict__ ovf, int* __restrict__ ovfn, int n_nodes) {
    __shared__ int cntL[256];
    __shared__ int im[256 * S_CAP];   // 32 KB
    int b = blockIdx.x;
    int t = threadIdx.x;
    cntL[t] = 0;
    __syncthreads();
    int s0 = base[b], s1 = base[b + 1];
    int node0 = b << 8;
    for (int k = s0 + t; k < s1; k += 256) {
        int v = pairs[k];
        int src = v & 0x00FFFFFF;
        int ld = ((unsigned)v) >> 24;
        int r = atomicAdd(&cntL[ld], 1);
        if (r < S_CAP) {
            im[ld * S_CAP + r] = src;
        } else {
            int o = atomicAdd(ovfn, 1);
            if (o < OVF_CAP) { ((int2*)ovf)[o] = make_int2(node0 + ld, src); }
        }
    }
    __syncthreads();
    int nvalid = min(256, n_nodes - node0);
    if (t < nvalid) cnt[node0 + t] = cntL[t];
    // slack im entries (slots >= cntL) are garbage — downstream masks by lim, never dereferenced
    for (int k = t; k < nvalid * S_CAP; k += 256)
        csr[(size_t)node0 * S_CAP + k] = im[k];
}

// ==== k_agg1: agg[i][0..31] (bf16) = mean_j x[j] — node-per-4-lanes, NO reduce ====
__global__ __launch_bounds__(256, 8) void k_agg1(
        const void* __restrict__ x,
        const int* __restrict__ cnt, const int* __restrict__ csr,
        const int* __restrict__ ovf, const int* __restrict__ ovfn,
        const int* __restrict__ flags,
        ush* __restrict__ aggb, int n_nodes) {
    int fb = flags[0];
    int t = threadIdx.x;
    int wave = t >> 6, lane = t & 63;
    int g4 = lane & 60;      // first lane of this node's 4-lane group
    int c  = lane & 3;       // channel chunk (8 ch)
    int node = (blockIdx.x * 4 + wave) * 16 + (lane >> 2);
    bool valid = node < n_nodes;
    int nd = valid ? node : n_nodes - 1;
    int dg = cnt[nd];
    int lim = min(dg, S_CAP);
    int idxr[8];
    {
        int4 i0 = *(const int4*)&csr[(size_t)nd * S_CAP + c * 8];
        int4 i1 = *(const int4*)&csr[(size_t)nd * S_CAP + c * 8 + 4];
        idxr[0] = i0.x; idxr[1] = i0.y; idxr[2] = i0.z; idxr[3] = i0.w;
        idxr[4] = i1.x; idxr[5] = i1.y; idxr[6] = i1.z; idxr[7] = i1.w;
    }
    int lmax = lim;
    lmax = max(lmax, __shfl_xor(lmax, 4));
    lmax = max(lmax, __shfl_xor(lmax, 8));
    lmax = max(lmax, __shfl_xor(lmax, 16));
    lmax = max(lmax, __shfl_xor(lmax, 32));
    float acc[8] = {0, 0, 0, 0, 0, 0, 0, 0};
    if (fb) {
        const ush* xb = (const ush*)x;
        for (int kb = 0; kb < 4; ++kb) {
            if (kb * 8 >= lmax) break;
#pragma unroll
            for (int kk = 0; kk < 8; ++kk) {
                int src = __shfl(idxr[kk], g4 + kb);
                if (kb * 8 + kk < lim) {
                    ush8 v = *(const ush8*)(xb + (size_t)src * IN_CH + c * 8);
#pragma unroll
                    for (int j = 0; j < 8; ++j) acc[j] += bf2f(v[j]);
                }
            }
        }
        if (dg > S_CAP) {   // ~never taken on bench data
            int on = min(*ovfn, OVF_CAP);
            for (int k = 0; k < on; ++k) {
                int2 pr = ((const int2*)ovf)[k];
                if (pr.x == nd && valid) {
                    ush8 v = *(const ush8*)(xb + (size_t)pr.y * IN_CH + c * 8);
#pragma unroll
                    for (int j = 0; j < 8; ++j) acc[j] += bf2f(v[j]);
                }
            }
        }
    } else {
        const float* xb = (const float*)x;
        for (int kb = 0; kb < 4; ++kb) {
            if (kb * 8 >= lmax) break;
#pragma unroll
            for (int kk = 0; kk < 8; ++kk) {
                int src = __shfl(idxr[kk], g4 + kb);
                if (kb * 8 + kk < lim) {
                    const float* rp = xb + (size_t)src * IN_CH + c * 8;
                    f4 a0 = *(const f4*)rp;
                    f4 a1 = *(const f4*)(rp + 4);
#pragma unroll
                    for (int j = 0; j < 4; ++j) { acc[j] += a0[j]; acc[4 + j] += a1[j]; }
                }
            }
        }
        if (dg > S_CAP) {
            int on = min(*ovfn, OVF_CAP);
            for (int k = 0; k < on; ++k) {
                int2 pr = ((const int2*)ovf)[k];
                if (pr.x == nd && valid) {
                    const float* rp = xb + (size_t)pr.y * IN_CH + c * 8;
                    f4 a0 = *(const f4*)rp;
                    f4 a1 = *(const f4*)(rp + 4);
#pragma unroll
                    for (int j = 0; j < 4; ++j) { acc[j] += a0[j]; acc[4 + j] += a1[j]; }
                }
            }
        }
    }
    if (valid) {
        float rd = 1.0f / (float)(dg > 1 ? dg : 1);
        ush8 ov;
#pragma unroll
        for (int j = 0; j < 8; ++j) ov[j] = f2bf(acc[j] * rd);
        *(ush8*)(aggb + (size_t)node * IN_CH + c * 8) = ov;
    }
}

// ==== k_fused: layer1 + layer2 dense matmuls, h staged in wave-private LDS tile ====
// Phase 1 (== old k_mm1_mfma): h-tile (16 nodes x 128) via MFMA, written to LDS
//   htile row = node-in-tile (kgrp*4+r), col = tt*16+col. Stride 132 ush:
//   store bank = 8*kgrp + col/2 + const -> all 32 banks, conflict-free.
// Phase 2 (== old k_g_mfma): A-fragments read back from LDS (row = col lane field),
//   16 MFMAs -> g (dense gbuf) and s (dense sbuf, or h[32..63] fallback).
// No __syncthreads between phases: tile is wave-private; lgkmcnt(0) orders DS ops.
// Numerics bit-identical to the split kernels (h rounds through bf16 identically).
__global__ __launch_bounds__(256, 2) void k_fused(
        const void* __restrict__ x, const ush* __restrict__ aggb,
        const void* __restrict__ W1l, const void* __restrict__ W1r,
        const void* __restrict__ b1,
        const void* __restrict__ W2l, const void* __restrict__ W2r,
        const void* __restrict__ b2,
        const int* __restrict__ flags,
        ush* __restrict__ gout, ush* __restrict__ sb, int sdense,
        ush* __restrict__ hglob, int n_nodes) {
    __shared__ ush w1st[HID * 64];          // 16 KB: W1cat[o][k]
    __shared__ ush w2st[2 * OUT_CH * HID];  // 16 KB: W2l | W2r
    __shared__ ush htile[4][16 * HT_STRIDE];// 16.5 KB: per-wave h tile
    int fb = flags[0];
    int t = threadIdx.x;
    for (int idx = t; idx < HID * IN_CH; idx += 256) {
        int o = idx >> 5, c = idx & 31;
        w1st[o * 64 + c]      = f2bf(ldf(W1l, idx, fb));
        w1st[o * 64 + 32 + c] = f2bf(ldf(W1r, idx, fb));
        w2st[idx]                 = f2bf(ldf(W2l, idx, fb));
        w2st[OUT_CH * HID + idx]  = f2bf(ldf(W2r, idx, fb));
    }
    __syncthreads();
    int wave = t >> 6, lane = t & 63;
    int col  = lane & 15;
    int kgrp = lane >> 4;
    // layer-1 B fragments: 8 output tiles x 2 k-steps
    s8v b1fr[8][2];
    float bs1[8];
#pragma unroll
    for (int tt = 0; tt < 8; ++tt) {
        int o = tt * 16 + col;
#pragma unroll
        for (int q = 0; q < 2; ++q)
            b1fr[tt][q] = __builtin_bit_cast(s8v, *(const ush8*)&w1st[o * 64 + q * 32 + kgrp * 8]);
        bs1[tt] = ldf(b1, o, fb);
    }
    // layer-2 B fragments: tiles 0,1 = g outputs; 2,3 = s outputs
    s8v b2fr[4][4];
#pragma unroll
    for (int tt = 0; tt < 4; ++tt) {
        int base = (tt < 2 ? 0 : OUT_CH * HID) + ((tt & 1) * 16 + col) * HID + kgrp * 8;
#pragma unroll
        for (int q = 0; q < 4; ++q)
            b2fr[tt][q] = __builtin_bit_cast(s8v, *(const ush8*)&w2st[base + q * 32]);
    }
    float bs2_0 = ldf(b2, col, fb);
    float bs2_1 = ldf(b2, 16 + col, fb);
    ush* ht = &htile[wave][0];
    int gw = blockIdx.x * 4 + wave;
    int nw = gridDim.x * 4;
    for (int n0 = gw * 16; n0 < n_nodes; n0 += nw * 16) {
        int arow = n0 + col;
        if (arow >= n_nodes) arow = n_nodes - 1;   // clamped tail: masked at store
        // ---- phase 1: layer-1 MFMAs ----
        s8v a0 = __builtin_bit_cast(s8v, *(const ush8*)(aggb + (size_t)arow * IN_CH + kgrp * 8));
        s8v a1;
        if (fb) {
            a1 = __builtin_bit_cast(s8v, *(const ush8*)((const ush*)x + (size_t)arow * IN_CH + kgrp * 8));
        } else {
            const float* rp = (const float*)x + (size_t)arow * IN_CH + kgrp * 8;
            f4 v0 = *(const f4*)rp;
            f4 v1 = *(const f4*)(rp + 4);
            ush8 tmp;
#pragma unroll
            for (int j = 0; j < 4; ++j) { tmp[j] = f2bf(v0[j]); tmp[4 + j] = f2bf(v1[j]); }
            a1 = __builtin_bit_cast(s8v, tmp);
        }
        f4 hacc[8];
#pragma unroll
        for (int tt = 0; tt < 8; ++tt) {
            f4 z = {0, 0, 0, 0};
            z = __builtin_amdgcn_mfma_f32_16x16x32_bf16(a0, b1fr[tt][0], z, 0, 0, 0);
            z = __builtin_amdgcn_mfma_f32_16x16x32_bf16(a1, b1fr[tt][1], z, 0, 0, 0);
            hacc[tt] = z;
        }
        // write h tile: node row kgrp*4+r, channel tt*16+col (bf16-rounded + relu)
#pragma unroll
        for (int r = 0; r < 4; ++r) {
#pragma unroll
            for (int tt = 0; tt < 8; ++tt) {
                float v = hacc[tt][r] + bs1[tt];
                ht[(kgrp * 4 + r) * HT_STRIDE + tt * 16 + col] = f2bf(v > 0.0f ? v : 0.0f);
            }
        }
        asm volatile("s_waitcnt lgkmcnt(0)" ::: "memory");   // order ds_write -> ds_read
        // ---- phase 2: read A fragments (node row = col), layer-2 MFMAs ----
        s8v A0 = __builtin_bit_cast(s8v, *(const ush8*)&ht[col * HT_STRIDE + 0 * 32 + kgrp * 8]);
        s8v A1 = __builtin_bit_cast(s8v, *(const ush8*)&ht[col * HT_STRIDE + 1 * 32 + kgrp * 8]);
        s8v A2 = __builtin_bit_cast(s8v, *(const ush8*)&ht[col * HT_STRIDE + 2 * 32 + kgrp * 8]);
        s8v A3 = __builtin_bit_cast(s8v, *(const ush8*)&ht[col * HT_STRIDE + 3 * 32 + kgrp * 8]);
        f4 acc0 = {0, 0, 0, 0}, acc1 = {0, 0, 0, 0}, acc2 = {0, 0, 0, 0}, acc3 = {0, 0, 0, 0};
        acc0 = __builtin_amdgcn_mfma_f32_16x16x32_bf16(A0, b2fr[0][0], acc0, 0, 0, 0);
        acc0 = __builtin_amdgcn_mfma_f32_16x16x32_bf16(A1, b2fr[0][1], acc0, 0, 0, 0);
        acc0 = __builtin_amdgcn_mfma_f32_16x16x32_bf16(A2, b2fr[0][2], acc0, 0, 0, 0);
        acc0 = __builtin_amdgcn_mfma_f32_16x16x32_bf16(A3, b2fr[0][3], acc0, 0, 0, 0);
        acc1 = __builtin_amdgcn_mfma_f32_16x16x32_bf16(A0, b2fr[1][0], acc1, 0, 0, 0);
        acc1 = __builtin_amdgcn_mfma_f32_16x16x32_bf16(A1, b2fr[1][1], acc1, 0, 0, 0);
        acc1 = __builtin_amdgcn_mfma_f32_16x16x32_bf16(A2, b2fr[1][2], acc1, 0, 0, 0);
        acc1 = __builtin_amdgcn_mfma_f32_16x16x32_bf16(A3, b2fr[1][3], acc1, 0, 0, 0);
        acc2 = __builtin_amdgcn_mfma_f32_16x16x32_bf16(A0, b2fr[2][0], acc2, 0, 0, 0);
        acc2 = __builtin_amdgcn_mfma_f32_16x16x32_bf16(A1, b2fr[2][1], acc2, 0, 0, 0);
        acc2 = __builtin_amdgcn_mfma_f32_16x16x32_bf16(A2, b2fr[2][2], acc2, 0, 0, 0);
        acc2 = __builtin_amdgcn_mfma_f32_16x16x32_bf16(A3, b2fr[2][3], acc2, 0, 0, 0);
        acc3 = __builtin_amdgcn_mfma_f32_16x16x32_bf16(A0, b2fr[3][0], acc3, 0, 0, 0);
        acc3 = __builtin_amdgcn_mfma_f32_16x16x32_bf16(A1, b2fr[3][1], acc3, 0, 0, 0);
        acc3 = __builtin_amdgcn_mfma_f32_16x16x32_bf16(A2, b2fr[3][2], acc3, 0, 0, 0);
        acc3 = __builtin_amdgcn_mfma_f32_16x16x32_bf16(A3, b2fr[3][3], acc3, 0, 0, 0);
#pragma unroll
        for (int r = 0; r < 4; ++r) {
            int node = n0 + kgrp * 4 + r;
            if (node < n_nodes) {
                gout[(size_t)node * OUT_CH + col]      = f2bf(acc0[r]);
                gout[(size_t)node * OUT_CH + 16 + col] = f2bf(acc1[r]);
                if (sdense) {
                    sb[(size_t)node * OUT_CH + col]      = f2bf(acc2[r] + bs2_0);
                    sb[(size_t)node * OUT_CH + 16 + col] = f2bf(acc3[r] + bs2_1);
                } else {
                    hglob[(size_t)node * HID + 32 + col] = f2bf(acc2[r] + bs2_0);
                    hglob[(size_t)node * HID + 48 + col] = f2bf(acc3[r] + bs2_1);
                }
            }
        }
    }
}

// ==== k_l2g: out[i] = mean_j g[j] + s[i] — node-per-4-lanes, NO cross-lane reduce ====
__global__ __launch_bounds__(256, 8) void k_l2g(
        const ush* __restrict__ gbuf, const ush* __restrict__ hs,
        const ush* __restrict__ sb, int sdense,
        const int* __restrict__ cnt, const int* __restrict__ csr,
        const int* __restrict__ ovf, const int* __restrict__ ovfn,
        const int* __restrict__ flags,
        void* __restrict__ out, int n_nodes) {
    int fb = flags[0];
    int t = threadIdx.x;
    int wave = t >> 6, lane = t & 63;
    int g4 = lane & 60;      // first lane of this node's 4-lane group
    int c  = lane & 3;       // channel chunk (8 ch)
    int node = (blockIdx.x * 4 + wave) * 16 + (lane >> 2);
    bool valid = node < n_nodes;
    int nd = valid ? node : n_nodes - 1;
    int dg = cnt[nd];
    int lim = min(dg, S_CAP);
    int idxr[8];
    {
        int4 i0 = *(const int4*)&csr[(size_t)nd * S_CAP + c * 8];
        int4 i1 = *(const int4*)&csr[(size_t)nd * S_CAP + c * 8 + 4];
        idxr[0] = i0.x; idxr[1] = i0.y; idxr[2] = i0.z; idxr[3] = i0.w;
        idxr[4] = i1.x; idxr[5] = i1.y; idxr[6] = i1.z; idxr[7] = i1.w;
    }
    int lmax = lim;
    lmax = max(lmax, __shfl_xor(lmax, 4));
    lmax = max(lmax, __shfl_xor(lmax, 8));
    lmax = max(lmax, __shfl_xor(lmax, 16));
    lmax = max(lmax, __shfl_xor(lmax, 32));
    float acc[8] = {0, 0, 0, 0, 0, 0, 0, 0};
    for (int kb = 0; kb < 4; ++kb) {
        if (kb * 8 >= lmax) break;
#pragma unroll
        for (int kk = 0; kk < 8; ++kk) {
            int src = __shfl(idxr[kk], g4 + kb);
            if (kb * 8 + kk < lim) {
                ush8 v = *(const ush8*)(gbuf + (size_t)src * OUT_CH + c * 8);
#pragma unroll
                for (int j = 0; j < 8; ++j) acc[j] += bf2f(v[j]);
            }
        }
    }
    if (dg > S_CAP) {   // ~never taken on bench data
        int on = min(*ovfn, OVF_CAP);
        for (int k = 0; k < on; ++k) {
            int2 pr = ((const int2*)ovf)[k];
            if (pr.x == nd && valid) {
                ush8 v = *(const ush8*)(gbuf + (size_t)pr.y * OUT_CH + c * 8);
#pragma unroll
                for (int j = 0; j < 8; ++j) acc[j] += bf2f(v[j]);
            }
        }
    }
    if (valid) {
        float rd = 1.0f / (float)(dg > 1 ? dg : 1);
        ush8 selfv = sdense
            ? *(const ush8*)(sb + (size_t)node * OUT_CH + c * 8)
            : *(const ush8*)(hs + (size_t)node * HID + 32 + c * 8);
        if (fb) {
            ush8 ov;
#pragma unroll
            for (int j = 0; j < 8; ++j)
                ov[j] = f2bf(acc[j] * rd + bf2f(selfv[j]));
            *(ush8*)((ush*)out + (size_t)node * OUT_CH + c * 8) = ov;
        } else {
            float* op = (float*)out + (size_t)node * OUT_CH + c * 8;
            f4 a0, a1;
#pragma unroll
            for (int j = 0; j < 4; ++j) {
                a0[j] = acc[j] * rd + bf2f(selfv[j]);
                a1[j] = acc[4 + j] * rd + bf2f(selfv[4 + j]);
            }
            *(f4*)op = a0;
            *(f4*)(op + 4) = a1;
        }
    }
}

extern "C" void kernel_launch(void* const* d_in, const int* in_sizes, int n_in,
                              void* d_out, int out_size, void* d_ws, size_t ws_size,
                              hipStream_t stream) {
    const void* x   = d_in[0];
    const int*  ei  = (const int*)d_in[1];
    const void* W1l = d_in[2];
    const void* W1r = d_in[3];
    const void* b1  = d_in[4];
    const void* W2l = d_in[5];
    const void* W2r = d_in[6];
    const void* b2  = d_in[7];

    int n_nodes = in_sizes[0] / IN_CH;
    int n_edges = in_sizes[1] / 2;

    // ws layout:
    //   [0,256)   flags (2 ints) + ovfn counter (at +128)
    //   cnt (N ints) | csr (N*S_CAP + 64 ints)
    //   | ovf region (OVF_CAP pairs = 640KB), then hist/base/cursor carve (~96KB)
    //   | h (N*HID bf16)   -- pairs[] aliases it (dead by k_fused); s fallback target
    //   | gbuf (N*OUT_CH bf16)
    //   | aggb (N*IN_CH bf16)  -- if ws permits, else aliases gbuf (safe: k_fused reads
    //     its aggb rows before writing the same gbuf rows; clamped reads masked)
    //   | sbuf (N*OUT_CH bf16) -- dense s, if ws permits, else s lives in h[32..63]
    char* ws = (char*)d_ws;
    size_t o_cnt = 256;
    size_t o_csr = (o_cnt + (size_t)n_nodes * 4 + 127) & ~(size_t)127;
    size_t o_ovf = (o_csr + ((size_t)n_nodes * S_CAP + 64) * 4 + 127) & ~(size_t)127;
    size_t o_hist = o_ovf + (size_t)OVF_CAP * 8;
    size_t o_h   = (o_hist + (size_t)(3 * (NB_MAX + 2)) * 4 + 255) & ~(size_t)255;
    size_t o_gb  = (o_h + (size_t)n_nodes * HID * 2 + 255) & ~(size_t)255;
    size_t o_ag  = (o_gb + (size_t)n_nodes * OUT_CH * 2 + 255) & ~(size_t)255;
    size_t o_sb  = (o_ag + (size_t)n_nodes * IN_CH * 2 + 255) & ~(size_t)255;
    size_t need_agg = o_ag + (size_t)n_nodes * IN_CH * 2;
    size_t need_sd  = o_sb + (size_t)n_nodes * OUT_CH * 2;

    int* flags = (int*)ws;
    int* ovfn  = (int*)(ws + 128);
    int* cnt   = (int*)(ws + o_cnt);
    int* csr   = (int*)(ws + o_csr);
    int* ovf   = (int*)(ws + o_ovf);
    int* hist  = (int*)(ws + o_hist);              // NB_MAX ints
    int* base  = hist + NB_MAX;                    // NB_MAX+1 ints
    int* curs  = base + NB_MAX + 1;                // NB_MAX ints
    ush* h     = (ush*)(ws + o_h);
    int* pairs = (int*)(ws + o_h);                 // aliases h; dead before k_fused
    ush* gbuf  = (ush*)(ws + o_gb);

    ush* aggb  = (ws_size >= need_agg) ? (ush*)(ws + o_ag) : gbuf;
    int  sdense = (ws_size >= need_sd) ? 1 : 0;
    ush* sbuf  = (ush*)(ws + o_sb);                // only dereferenced when sdense

    int NB = (n_nodes + 255) >> 8;       // 256 nodes per bucket (proven geometry)
    int use_bucket = (NB <= NB_MAX) && (n_nodes < (1 << 24)) &&
                     ((size_t)n_edges * 4 <= (size_t)n_nodes * HID * 2) && (n_edges > 0);

    hipMemsetAsync(ws, 0, 256, stream);                          // flags + ovfn

    k_detect<<<1, 256, 0, stream>>>((const unsigned short*)x, ei, flags);

    if (use_bucket) {
        hipMemsetAsync(hist, 0, (size_t)NB * 4, stream);
        int nchunks = (n_edges + SC_CHUNK - 1) / SC_CHUNK;
        k_hist<<<256, 256, 0, stream>>>(ei, n_edges, flags, hist, NB);
        k_scan<<<1, 256, 0, stream>>>(hist, base, curs, NB);
        k_scatter<<<nchunks, 256, 0, stream>>>(ei, n_edges, flags, curs, pairs, NB);
        k_build<<<NB, 256, 0, stream>>>(pairs, base, cnt, csr, ovf, ovfn, n_nodes);
    } else {
        hipMemsetAsync(cnt, 0, (size_t)n_nodes * 4, stream);
        k_fillp<<<(n_edges + 255) / 256, 256, 0, stream>>>(ei, n_edges, flags, cnt, csr, ovf, ovfn);
    }

    // gathers: node-per-4-lanes, 64 nodes/block, one shot per wave
    int nblk_g = (n_nodes + 63) / 64;
    k_agg1<<<nblk_g, 256, 0, stream>>>(x, cnt, csr, ovf, ovfn, flags, aggb, n_nodes);
    // fused dense layers: 49.7KB LDS -> 3 blocks/CU; ~200 VGPR -> 2 waves/SIMD
    k_fused<<<768, 256, 0, stream>>>(x, aggb, W1l, W1r, b1, W2l, W2r, b2, flags,
                                     gbuf, sbuf, sdense, h, n_nodes);
    k_l2g<<<nblk_g, 256, 0, stream>>>(gbuf, h, sbuf, sdense, cnt, csr, ovf, ovfn, flags, d_out, n_nodes);
}

// Round 15
// 232.584 us; speedup vs baseline: 1.0163x; 1.0163x over previous
//
#include <hip/hip_runtime.h>
#include <hip/hip_bf16.h>

typedef __hip_bfloat16 bf16;
typedef unsigned short ush;
typedef __attribute__((ext_vector_type(8))) unsigned short ush8;
typedef __attribute__((ext_vector_type(8))) short s8v;     // 8 bf16 for MFMA A/B
typedef __attribute__((ext_vector_type(4))) float f4;

#define IN_CH 32
#define HID 128
#define OUT_CH 32
#define S_CAP 32             // fixed csr slots per node; rank>=S_CAP -> overflow list
#define OVF_CAP 80000        // overflow pair capacity (bench data: ~0 used)
#define NB_MAX 2048          // max buckets (256 nodes each) -> n_nodes <= 524288
#define SC_CHUNK 8192        // edges per block in chunked scatter
// segment invariant: SC_CHUNK/NB ~ 21 records (84B); round-12 lesson: don't shrink both
// round-14 lesson: fusing mm1+g overflows the VGPR budget for pinned weight fragments
// (compiler re-reads them from LDS every iter -> 2M bank conflicts); keep them split.

__device__ __forceinline__ float bf2f(ush u) {
    return __uint_as_float(((unsigned)u) << 16);
}
__device__ __forceinline__ ush f2bf(float f) {
    __hip_bfloat16 b = __float2bfloat16(f);
    return __builtin_bit_cast(ush, b);
}
__device__ __forceinline__ float ldf(const void* __restrict__ p, size_t idx, int isbf16) {
    return isbf16 ? bf2f(((const ush*)p)[idx]) : ((const float*)p)[idx];
}
__device__ __forceinline__ int ld_edge(const int* __restrict__ ei, size_t elem, int wide) {
    return wide ? ei[2 * elem] : ei[elem];
}

// ---------- sniff dtypes: flags[0]=float_is_bf16, flags[1]=edge_is_i64 ----------
__global__ void k_detect(const unsigned short* __restrict__ xraw,
                         const int* __restrict__ ei, int* __restrict__ flags) {
    __shared__ int cnt_exp, any_nz;
    if (threadIdx.x == 0) { cnt_exp = 0; any_nz = 0; }
    __syncthreads();
    int local = 0;
    for (int k = threadIdx.x; k < 4096; k += 256) {
        int e = (xraw[k] >> 7) & 0xFF;
        if (e >= 100 && e <= 140) ++local;
    }
    atomicAdd(&cnt_exp, local);
    for (int k = threadIdx.x; k < 2048; k += 256)
        if (ei[2 * k + 1] != 0) any_nz = 1;   // benign race
    __syncthreads();
    if (threadIdx.x == 0) {
        flags[0] = (cnt_exp > 3500) ? 1 : 0;
        flags[1] = any_nz ? 0 : 1;
    }
}

// ---------- FALLBACK: fused count+place (one global atomic + scattered store per edge) ----------
__global__ void k_fillp(const int* __restrict__ ei, int n_edges,
                        const int* __restrict__ flags,
                        int* __restrict__ cnt, int* __restrict__ csr,
                        int* __restrict__ ovf, int* __restrict__ ovfn) {
    int e = blockIdx.x * blockDim.x + threadIdx.x;
    if (e >= n_edges) return;
    int w = flags[1];
    int d  = ld_edge(ei, (size_t)n_edges + e, w);
    int sc = ld_edge(ei, (size_t)e, w);
    int r = atomicAdd(&cnt[d], 1);
    if (r < S_CAP) {
        csr[d * S_CAP + r] = sc;
    } else {
        int o = atomicAdd(ovfn, 1);
        if (o < OVF_CAP) { ((int2*)ovf)[o] = make_int2(d, sc); }
    }
}

// ---------- bucketed partition: hist -> scan -> chunked scatter -> build(LDS) ----------
// bucket b = dst >> 8 (256 nodes/bucket); packed record = src | (dst&255)<<24

__global__ __launch_bounds__(256) void k_hist(
        const int* __restrict__ ei, int n_edges,
        const int* __restrict__ flags,
        int* __restrict__ hist, int NB) {
    __shared__ int hl[NB_MAX];   // 8 KB
    int t = threadIdx.x;
    for (int k = t; k < NB; k += 256) hl[k] = 0;
    __syncthreads();
    int w = flags[1];
    int stride = gridDim.x * 256;
    for (int e = blockIdx.x * 256 + t; e < n_edges; e += stride) {
        int d = ld_edge(ei, (size_t)n_edges + e, w);
        atomicAdd(&hl[d >> 8], 1);
    }
    __syncthreads();
    for (int k = t; k < NB; k += 256)
        if (hl[k]) atomicAdd(&hist[k], hl[k]);
}

// single block; exclusive prefix over NB buckets; cursor[b]=base[b]
__global__ __launch_bounds__(256) void k_scan(
        const int* __restrict__ hist,
        int* __restrict__ base, int* __restrict__ cursor, int NB) {
    __shared__ int part[256];
    int t = threadIdx.x;
    int chunk = (NB + 255) / 256;
    int lo = t * chunk, hi = min(NB, (t + 1) * chunk);
    int s = 0;
    for (int k = lo; k < hi; ++k) s += hist[k];
    part[t] = s;
    __syncthreads();
    if (t == 0) {
        int r = 0;
        for (int q = 0; q < 256; ++q) { int v = part[q]; part[q] = r; r += v; }
        base[NB] = r;
    }
    __syncthreads();
    int r = part[t];
    for (int k = lo; k < hi; ++k) {
        base[k] = r; cursor[k] = r;
        r += hist[k];
    }
}

// chunked two-pass scatter: per (block,bucket) ONE global atomic reservation,
// then contiguous segment writes (fills lines -> no 64B/record amplification).
__global__ __launch_bounds__(256) void k_scatter(
        const int* __restrict__ ei, int n_edges,
        const int* __restrict__ flags,
        int* __restrict__ cursor, int* __restrict__ pairs, int NB) {
    __shared__ int cA[NB_MAX];   // pass A: chunk histogram; pass B: rank counter
    __shared__ int oA[NB_MAX];   // reserved global offset per bucket
    int t = threadIdx.x;
    int w = flags[1];
    int e0 = blockIdx.x * SC_CHUNK;
    int ecnt = min(SC_CHUNK, n_edges - e0);
    if (ecnt <= 0) return;
    for (int k = t; k < NB; k += 256) cA[k] = 0;
    __syncthreads();
    // pass A: chunk histogram (LDS atomics)
    for (int k = t; k < ecnt; k += 256) {
        int d = ld_edge(ei, (size_t)n_edges + e0 + k, w);
        atomicAdd(&cA[d >> 8], 1);
    }
    __syncthreads();
    // reserve: one global atomic per non-empty (block,bucket); reset rank counters
    for (int b = t; b < NB; b += 256) {
        int c = cA[b];
        oA[b] = c ? atomicAdd(&cursor[b], c) : 0;
        cA[b] = 0;
    }
    __syncthreads();
    // pass B: place records contiguously within reserved segments
    for (int k = t; k < ecnt; k += 256) {
        int d  = ld_edge(ei, (size_t)n_edges + e0 + k, w);
        int sc = ld_edge(ei, (size_t)e0 + k, w);
        int b = d >> 8;
        int r = atomicAdd(&cA[b], 1);
        pairs[oA[b] + r] = sc | ((d & 255) << 24);
    }
}

// one block per bucket (256 nodes): LDS count+place, coalesced writeout of cnt + csr
__global__ __launch_bounds__(256) void k_build(
        const int* __restrict__ pairs, const int* __restrict__ base,
        int* __restrict__ cnt, int* __restrict__ csr,
        int* __restrict__ ovf, int* __restrict__ ovfn, int n_nodes) {
    __shared__ int cntL[256];
    __shared__ int im[256 * S_CAP];   // 32 KB
    int b = blockIdx.x;
    int t = threadIdx.x;
    cntL[t] = 0;
    __syncthreads();
    int s0 = base[b], s1 = base[b + 1];
    int node0 = b << 8;
    for (int k = s0 + t; k < s1; k += 256) {
        int v = pairs[k];
        int src = v & 0x00FFFFFF;
        int ld = ((unsigned)v) >> 24;
        int r = atomicAdd(&cntL[ld], 1);
        if (r < S_CAP) {
            im[ld * S_CAP + r] = src;
        } else {
            int o = atomicAdd(ovfn, 1);
            if (o < OVF_CAP) { ((int2*)ovf)[o] = make_int2(node0 + ld, src); }
        }
    }
    __syncthreads();
    int nvalid = min(256, n_nodes - node0);
    if (t < nvalid) cnt[node0 + t] = cntL[t];
    // slack im entries (slots >= cntL) are garbage — downstream masks by lim, never dereferenced
    for (int k = t; k < nvalid * S_CAP; k += 256)
        csr[(size_t)node0 * S_CAP + k] = im[k];
}

// ==== k_agg1: agg[i][0..31] (bf16) = mean_j x[j] — node-per-4-lanes, NO reduce ====
// 16 nodes/wave; 4-lane group owns one node; lane owns 8 channels (chunk c = lane&3).
// bf16 store is bit-identical to the old f32-store+f2bf-convert path in k_mm1_mfma.
__global__ __launch_bounds__(256, 8) void k_agg1(
        const void* __restrict__ x,
        const int* __restrict__ cnt, const int* __restrict__ csr,
        const int* __restrict__ ovf, const int* __restrict__ ovfn,
        const int* __restrict__ flags,
        ush* __restrict__ aggb, int n_nodes) {
    int fb = flags[0];
    int t = threadIdx.x;
    int wave = t >> 6, lane = t & 63;
    int g4 = lane & 60;      // first lane of this node's 4-lane group
    int c  = lane & 3;       // channel chunk (8 ch)
    int node = (blockIdx.x * 4 + wave) * 16 + (lane >> 2);
    bool valid = node < n_nodes;
    int nd = valid ? node : n_nodes - 1;
    int dg = cnt[nd];
    int lim = min(dg, S_CAP);
    int idxr[8];
    {
        int4 i0 = *(const int4*)&csr[(size_t)nd * S_CAP + c * 8];
        int4 i1 = *(const int4*)&csr[(size_t)nd * S_CAP + c * 8 + 4];
        idxr[0] = i0.x; idxr[1] = i0.y; idxr[2] = i0.z; idxr[3] = i0.w;
        idxr[4] = i1.x; idxr[5] = i1.y; idxr[6] = i1.z; idxr[7] = i1.w;
    }
    int lmax = lim;
    lmax = max(lmax, __shfl_xor(lmax, 4));
    lmax = max(lmax, __shfl_xor(lmax, 8));
    lmax = max(lmax, __shfl_xor(lmax, 16));
    lmax = max(lmax, __shfl_xor(lmax, 32));
    float acc[8] = {0, 0, 0, 0, 0, 0, 0, 0};
    if (fb) {
        const ush* xb = (const ush*)x;
        for (int kb = 0; kb < 4; ++kb) {
            if (kb * 8 >= lmax) break;
#pragma unroll
            for (int kk = 0; kk < 8; ++kk) {
                int src = __shfl(idxr[kk], g4 + kb);
                if (kb * 8 + kk < lim) {
                    ush8 v = *(const ush8*)(xb + (size_t)src * IN_CH + c * 8);
#pragma unroll
                    for (int j = 0; j < 8; ++j) acc[j] += bf2f(v[j]);
                }
            }
        }
        if (dg > S_CAP) {   // ~never taken on bench data
            int on = min(*ovfn, OVF_CAP);
            for (int k = 0; k < on; ++k) {
                int2 pr = ((const int2*)ovf)[k];
                if (pr.x == nd && valid) {
                    ush8 v = *(const ush8*)(xb + (size_t)pr.y * IN_CH + c * 8);
#pragma unroll
                    for (int j = 0; j < 8; ++j) acc[j] += bf2f(v[j]);
                }
            }
        }
    } else {
        const float* xb = (const float*)x;
        for (int kb = 0; kb < 4; ++kb) {
            if (kb * 8 >= lmax) break;
#pragma unroll
            for (int kk = 0; kk < 8; ++kk) {
                int src = __shfl(idxr[kk], g4 + kb);
                if (kb * 8 + kk < lim) {
                    const float* rp = xb + (size_t)src * IN_CH + c * 8;
                    f4 a0 = *(const f4*)rp;
                    f4 a1 = *(const f4*)(rp + 4);
#pragma unroll
                    for (int j = 0; j < 4; ++j) { acc[j] += a0[j]; acc[4 + j] += a1[j]; }
                }
            }
        }
        if (dg > S_CAP) {
            int on = min(*ovfn, OVF_CAP);
            for (int k = 0; k < on; ++k) {
                int2 pr = ((const int2*)ovf)[k];
                if (pr.x == nd && valid) {
                    const float* rp = xb + (size_t)pr.y * IN_CH + c * 8;
                    f4 a0 = *(const f4*)rp;
                    f4 a1 = *(const f4*)(rp + 4);
#pragma unroll
                    for (int j = 0; j < 4; ++j) { acc[j] += a0[j]; acc[4 + j] += a1[j]; }
                }
            }
        }
    }
    if (valid) {
        float rd = 1.0f / (float)(dg > 1 ? dg : 1);
        ush8 ov;
#pragma unroll
        for (int j = 0; j < 8; ++j) ov[j] = f2bf(acc[j] * rd);
        *(ush8*)(aggb + (size_t)node * IN_CH + c * 8) = ov;
    }
}

// ==== k_mm1_mfma: h = relu([agg|x] @ [W1l|W1r]^T + b1) via MFMA, K=64 ====
__global__ __launch_bounds__(256, 4) void k_mm1_mfma(
        const void* __restrict__ x, const ush* __restrict__ aggb,
        const void* __restrict__ W1l, const void* __restrict__ W1r,
        const void* __restrict__ b1,
        const int* __restrict__ flags,
        ush* __restrict__ hout, int n_nodes) {
    __shared__ ush wst[HID * 64];   // 16 KB: W1cat[o][k], k<32 = W1l, k>=32 = W1r
    int fb = flags[0];
    int t = threadIdx.x;
    for (int idx = t; idx < HID * IN_CH; idx += 256) {
        int o = idx >> 5, c = idx & 31;
        wst[o * 64 + c]      = f2bf(ldf(W1l, idx, fb));
        wst[o * 64 + 32 + c] = f2bf(ldf(W1r, idx, fb));
    }
    __syncthreads();
    int wave = t >> 6, lane = t & 63;
    int col  = lane & 15;    // A row offset / B+D column
    int kgrp = lane >> 4;    // k-group within 32-wide k-step
    s8v bfr[8][2];
    float bias[8];
#pragma unroll
    for (int tt = 0; tt < 8; ++tt) {
        int o = tt * 16 + col;
#pragma unroll
        for (int q = 0; q < 2; ++q)
            bfr[tt][q] = __builtin_bit_cast(s8v, *(const ush8*)&wst[o * 64 + q * 32 + kgrp * 8]);
        bias[tt] = ldf(b1, o, fb);
    }
    int gw = blockIdx.x * 4 + wave;
    int nw = gridDim.x * 4;
    for (int n0 = gw * 16; n0 < n_nodes; n0 += nw * 16) {
        int arow = n0 + col;
        if (arow >= n_nodes) arow = n_nodes - 1;   // clamped tail: masked at store
        s8v a0 = __builtin_bit_cast(s8v, *(const ush8*)(aggb + (size_t)arow * IN_CH + kgrp * 8));
        s8v a1;
        if (fb) {
            a1 = __builtin_bit_cast(s8v, *(const ush8*)((const ush*)x + (size_t)arow * IN_CH + kgrp * 8));
        } else {
            const float* rp = (const float*)x + (size_t)arow * IN_CH + kgrp * 8;
            f4 v0 = *(const f4*)rp;
            f4 v1 = *(const f4*)(rp + 4);
            ush8 tmp;
#pragma unroll
            for (int j = 0; j < 4; ++j) { tmp[j] = f2bf(v0[j]); tmp[4 + j] = f2bf(v1[j]); }
            a1 = __builtin_bit_cast(s8v, tmp);
        }
        f4 acc[8];
#pragma unroll
        for (int tt = 0; tt < 8; ++tt) {
            f4 z = {0, 0, 0, 0};
            z = __builtin_amdgcn_mfma_f32_16x16x32_bf16(a0, bfr[tt][0], z, 0, 0, 0);
            z = __builtin_amdgcn_mfma_f32_16x16x32_bf16(a1, bfr[tt][1], z, 0, 0, 0);
            acc[tt] = z;
        }
#pragma unroll
        for (int r = 0; r < 4; ++r) {
            int node = n0 + kgrp * 4 + r;
            if (node < n_nodes) {
#pragma unroll
                for (int tt = 0; tt < 8; ++tt) {
                    float v = acc[tt][r] + bias[tt];
                    hout[(size_t)node * HID + tt * 16 + col] = f2bf(v > 0.0f ? v : 0.0f);
                }
            }
        }
    }
}

// ==== k_g_mfma: [g|s] = h @ [W2l^T | W2r^T] via MFMA; 16 nodes/wave/iter ====
// s -> dense sb[N][32] if sdense, else h[32..63] (fallback)
__global__ __launch_bounds__(256, 4) void k_g_mfma(
        ush* __restrict__ h, ush* __restrict__ gout,
        ush* __restrict__ sb, int sdense,
        const void* __restrict__ W2l, const void* __restrict__ W2r,
        const void* __restrict__ b2,
        const int* __restrict__ flags, int n_nodes) {
    __shared__ ush wst[2 * OUT_CH * HID];  // 16 KB: W2l then W2r, bf16 [o][ch]
    int fb = flags[0];
    int t = threadIdx.x;
    for (int idx = t; idx < OUT_CH * HID; idx += 256) {
        wst[idx]                  = f2bf(ldf(W2l, idx, fb));
        wst[OUT_CH * HID + idx]   = f2bf(ldf(W2r, idx, fb));
    }
    __syncthreads();
    int wave = t >> 6, lane = t & 63;
    int col  = lane & 15;    // A row offset / B+D column
    int kgrp = lane >> 4;    // k-group: k = kgrp*8 + j (per 32-wide k-step)
    s8v bfr[4][4];
#pragma unroll
    for (int tt = 0; tt < 4; ++tt) {
        int base = (tt < 2 ? 0 : OUT_CH * HID) + ((tt & 1) * 16 + col) * HID + kgrp * 8;
#pragma unroll
        for (int q = 0; q < 4; ++q)
            bfr[tt][q] = __builtin_bit_cast(s8v, *(const ush8*)&wst[base + q * 32]);
    }
    float bias0 = ldf(b2, col, fb);        // s outputs 0..15
    float bias1 = ldf(b2, 16 + col, fb);   // s outputs 16..31
    int gw = blockIdx.x * 4 + wave;
    int nw = gridDim.x * 4;
    for (int n0 = gw * 16; n0 < n_nodes; n0 += nw * 16) {
        int arow = n0 + col;
        if (arow >= n_nodes) arow = n_nodes - 1;   // clamped tail: results masked at store
        const ush* hp = h + (size_t)arow * HID + kgrp * 8;
        s8v a0 = __builtin_bit_cast(s8v, *(const ush8*)(hp));
        s8v a1 = __builtin_bit_cast(s8v, *(const ush8*)(hp + 32));
        s8v a2 = __builtin_bit_cast(s8v, *(const ush8*)(hp + 64));
        s8v a3 = __builtin_bit_cast(s8v, *(const ush8*)(hp + 96));
        f4 acc0 = {0, 0, 0, 0}, acc1 = {0, 0, 0, 0}, acc2 = {0, 0, 0, 0}, acc3 = {0, 0, 0, 0};
        acc0 = __builtin_amdgcn_mfma_f32_16x16x32_bf16(a0, bfr[0][0], acc0, 0, 0, 0);
        acc0 = __builtin_amdgcn_mfma_f32_16x16x32_bf16(a1, bfr[0][1], acc0, 0, 0, 0);
        acc0 = __builtin_amdgcn_mfma_f32_16x16x32_bf16(a2, bfr[0][2], acc0, 0, 0, 0);
        acc0 = __builtin_amdgcn_mfma_f32_16x16x32_bf16(a3, bfr[0][3], acc0, 0, 0, 0);
        acc1 = __builtin_amdgcn_mfma_f32_16x16x32_bf16(a0, bfr[1][0], acc1, 0, 0, 0);
        acc1 = __builtin_amdgcn_mfma_f32_16x16x32_bf16(a1, bfr[1][1], acc1, 0, 0, 0);
        acc1 = __builtin_amdgcn_mfma_f32_16x16x32_bf16(a2, bfr[1][2], acc1, 0, 0, 0);
        acc1 = __builtin_amdgcn_mfma_f32_16x16x32_bf16(a3, bfr[1][3], acc1, 0, 0, 0);
        acc2 = __builtin_amdgcn_mfma_f32_16x16x32_bf16(a0, bfr[2][0], acc2, 0, 0, 0);
        acc2 = __builtin_amdgcn_mfma_f32_16x16x32_bf16(a1, bfr[2][1], acc2, 0, 0, 0);
        acc2 = __builtin_amdgcn_mfma_f32_16x16x32_bf16(a2, bfr[2][2], acc2, 0, 0, 0);
        acc2 = __builtin_amdgcn_mfma_f32_16x16x32_bf16(a3, bfr[2][3], acc2, 0, 0, 0);
        acc3 = __builtin_amdgcn_mfma_f32_16x16x32_bf16(a0, bfr[3][0], acc3, 0, 0, 0);
        acc3 = __builtin_amdgcn_mfma_f32_16x16x32_bf16(a1, bfr[3][1], acc3, 0, 0, 0);
        acc3 = __builtin_amdgcn_mfma_f32_16x16x32_bf16(a2, bfr[3][2], acc3, 0, 0, 0);
        acc3 = __builtin_amdgcn_mfma_f32_16x16x32_bf16(a3, bfr[3][3], acc3, 0, 0, 0);
#pragma unroll
        for (int r = 0; r < 4; ++r) {
            int node = n0 + kgrp * 4 + r;
            if (node < n_nodes) {
                gout[(size_t)node * OUT_CH + col]      = f2bf(acc0[r]);
                gout[(size_t)node * OUT_CH + 16 + col] = f2bf(acc1[r]);
                if (sdense) {
                    sb[(size_t)node * OUT_CH + col]      = f2bf(acc2[r] + bias0);
                    sb[(size_t)node * OUT_CH + 16 + col] = f2bf(acc3[r] + bias1);
                } else {
                    h[(size_t)node * HID + 32 + col]     = f2bf(acc2[r] + bias0);
                    h[(size_t)node * HID + 48 + col]     = f2bf(acc3[r] + bias1);
                }
            }
        }
    }
}

// ==== k_l2g: out[i] = mean_j g[j] + s[i] — node-per-4-lanes, NO cross-lane reduce ====
__global__ __launch_bounds__(256, 8) void k_l2g(
        const ush* __restrict__ gbuf, const ush* __restrict__ hs,
        const ush* __restrict__ sb, int sdense,
        const int* __restrict__ cnt, const int* __restrict__ csr,
        const int* __restrict__ ovf, const int* __restrict__ ovfn,
        const int* __restrict__ flags,
        void* __restrict__ out, int n_nodes) {
    int fb = flags[0];
    int t = threadIdx.x;
    int wave = t >> 6, lane = t & 63;
    int g4 = lane & 60;      // first lane of this node's 4-lane group
    int c  = lane & 3;       // channel chunk (8 ch)
    int node = (blockIdx.x * 4 + wave) * 16 + (lane >> 2);
    bool valid = node < n_nodes;
    int nd = valid ? node : n_nodes - 1;
    int dg = cnt[nd];
    int lim = min(dg, S_CAP);
    int idxr[8];
    {
        int4 i0 = *(const int4*)&csr[(size_t)nd * S_CAP + c * 8];
        int4 i1 = *(const int4*)&csr[(size_t)nd * S_CAP + c * 8 + 4];
        idxr[0] = i0.x; idxr[1] = i0.y; idxr[2] = i0.z; idxr[3] = i0.w;
        idxr[4] = i1.x; idxr[5] = i1.y; idxr[6] = i1.z; idxr[7] = i1.w;
    }
    int lmax = lim;
    lmax = max(lmax, __shfl_xor(lmax, 4));
    lmax = max(lmax, __shfl_xor(lmax, 8));
    lmax = max(lmax, __shfl_xor(lmax, 16));
    lmax = max(lmax, __shfl_xor(lmax, 32));
    float acc[8] = {0, 0, 0, 0, 0, 0, 0, 0};
    for (int kb = 0; kb < 4; ++kb) {
        if (kb * 8 >= lmax) break;
#pragma unroll
        for (int kk = 0; kk < 8; ++kk) {
            int src = __shfl(idxr[kk], g4 + kb);
            if (kb * 8 + kk < lim) {
                ush8 v = *(const ush8*)(gbuf + (size_t)src * OUT_CH + c * 8);
#pragma unroll
                for (int j = 0; j < 8; ++j) acc[j] += bf2f(v[j]);
            }
        }
    }
    if (dg > S_CAP) {   // ~never taken on bench data
        int on = min(*ovfn, OVF_CAP);
        for (int k = 0; k < on; ++k) {
            int2 pr = ((const int2*)ovf)[k];
            if (pr.x == nd && valid) {
                ush8 v = *(const ush8*)(gbuf + (size_t)pr.y * OUT_CH + c * 8);
#pragma unroll
                for (int j = 0; j < 8; ++j) acc[j] += bf2f(v[j]);
            }
        }
    }
    if (valid) {
        float rd = 1.0f / (float)(dg > 1 ? dg : 1);
        ush8 selfv = sdense
            ? *(const ush8*)(sb + (size_t)node * OUT_CH + c * 8)
            : *(const ush8*)(hs + (size_t)node * HID + 32 + c * 8);
        if (fb) {
            ush8 ov;
#pragma unroll
            for (int j = 0; j < 8; ++j)
                ov[j] = f2bf(acc[j] * rd + bf2f(selfv[j]));
            *(ush8*)((ush*)out + (size_t)node * OUT_CH + c * 8) = ov;
        } else {
            float* op = (float*)out + (size_t)node * OUT_CH + c * 8;
            f4 a0, a1;
#pragma unroll
            for (int j = 0; j < 4; ++j) {
                a0[j] = acc[j] * rd + bf2f(selfv[j]);
                a1[j] = acc[4 + j] * rd + bf2f(selfv[4 + j]);
            }
            *(f4*)op = a0;
            *(f4*)(op + 4) = a1;
        }
    }
}

extern "C" void kernel_launch(void* const* d_in, const int* in_sizes, int n_in,
                              void* d_out, int out_size, void* d_ws, size_t ws_size,
                              hipStream_t stream) {
    const void* x   = d_in[0];
    const int*  ei  = (const int*)d_in[1];
    const void* W1l = d_in[2];
    const void* W1r = d_in[3];
    const void* b1  = d_in[4];
    const void* W2l = d_in[5];
    const void* W2r = d_in[6];
    const void* b2  = d_in[7];

    int n_nodes = in_sizes[0] / IN_CH;
    int n_edges = in_sizes[1] / 2;

    // ws layout:
    //   [0,256)   flags (2 ints) + ovfn counter (at +128)
    //   cnt (N ints) | csr (N*S_CAP + 64 ints)
    //   | ovf region (OVF_CAP pairs = 640KB), then hist/base/cursor carve (~96KB)
    //   | h (N*HID bf16)   -- pairs[] for bucketed partition ALIASES h (dead by k_mm1_mfma)
    //   | gbuf (N*OUT_CH bf16)
    //   | aggb (N*IN_CH bf16)  -- if ws permits, else aliases gbuf (dead by k_g_mfma)
    //   | sbuf (N*OUT_CH bf16) -- dense s, if ws permits, else s lives in h[32..63]
    char* ws = (char*)d_ws;
    size_t o_cnt = 256;
    size_t o_csr = (o_cnt + (size_t)n_nodes * 4 + 127) & ~(size_t)127;
    size_t o_ovf = (o_csr + ((size_t)n_nodes * S_CAP + 64) * 4 + 127) & ~(size_t)127;
    size_t o_hist = o_ovf + (size_t)OVF_CAP * 8;
    size_t o_h   = (o_hist + (size_t)(3 * (NB_MAX + 2)) * 4 + 255) & ~(size_t)255;
    size_t o_gb  = (o_h + (size_t)n_nodes * HID * 2 + 255) & ~(size_t)255;
    size_t o_ag  = (o_gb + (size_t)n_nodes * OUT_CH * 2 + 255) & ~(size_t)255;
    size_t o_sb  = (o_ag + (size_t)n_nodes * IN_CH * 2 + 255) & ~(size_t)255;
    size_t need_agg = o_ag + (size_t)n_nodes * IN_CH * 2;
    size_t need_sd  = o_sb + (size_t)n_nodes * OUT_CH * 2;

    int* flags = (int*)ws;
    int* ovfn  = (int*)(ws + 128);
    int* cnt   = (int*)(ws + o_cnt);
    int* csr   = (int*)(ws + o_csr);
    int* ovf   = (int*)(ws + o_ovf);
    int* hist  = (int*)(ws + o_hist);              // NB_MAX ints
    int* base  = hist + NB_MAX;                    // NB_MAX+1 ints
    int* curs  = base + NB_MAX + 1;                // NB_MAX ints
    ush* h     = (ush*)(ws + o_h);
    int* pairs = (int*)(ws + o_h);                 // aliases h; dead before k_mm1_mfma
    ush* gbuf  = (ush*)(ws + o_gb);

    ush* aggb  = (ws_size >= need_agg) ? (ush*)(ws + o_ag) : gbuf;  // alias ok: dead by k_g_mfma
    int  sdense = (ws_size >= need_sd) ? 1 : 0;
    ush* sbuf  = (ush*)(ws + o_sb);                // only dereferenced when sdense

    int NB = (n_nodes + 255) >> 8;       // 256 nodes per bucket (round-6/11 proven geometry)
    // bucketed path requires: NB fits LDS; src fits 24 bits; pairs fits in h region
    int use_bucket = (NB <= NB_MAX) && (n_nodes < (1 << 24)) &&
                     ((size_t)n_edges * 4 <= (size_t)n_nodes * HID * 2) && (n_edges > 0);

    hipMemsetAsync(ws, 0, 256, stream);                          // flags + ovfn

    k_detect<<<1, 256, 0, stream>>>((const unsigned short*)x, ei, flags);

    if (use_bucket) {
        hipMemsetAsync(hist, 0, (size_t)NB * 4, stream);
        int nchunks = (n_edges + SC_CHUNK - 1) / SC_CHUNK;
        k_hist<<<256, 256, 0, stream>>>(ei, n_edges, flags, hist, NB);
        k_scan<<<1, 256, 0, stream>>>(hist, base, curs, NB);
        k_scatter<<<nchunks, 256, 0, stream>>>(ei, n_edges, flags, curs, pairs, NB);
        k_build<<<NB, 256, 0, stream>>>(pairs, base, cnt, csr, ovf, ovfn, n_nodes);
    } else {
        hipMemsetAsync(cnt, 0, (size_t)n_nodes * 4, stream);
        k_fillp<<<(n_edges + 255) / 256, 256, 0, stream>>>(ei, n_edges, flags, cnt, csr, ovf, ovfn);
    }

    // gathers: node-per-4-lanes, 64 nodes/block, one shot per wave
    int nblk_g = (n_nodes + 63) / 64;
    k_agg1<<<nblk_g, 256, 0, stream>>>(x, cnt, csr, ovf, ovfn, flags, aggb, n_nodes);
    // dense layer 1 via MFMA (K=64 concat): 16 nodes/wave/iter; 4 blocks/CU
    k_mm1_mfma<<<1024, 256, 0, stream>>>(x, aggb, W1l, W1r, b1, flags, h, n_nodes);
    // dense layer 2 via MFMA: 16 nodes/wave/iter; 4 blocks/CU
    k_g_mfma<<<1024, 256, 0, stream>>>(h, gbuf, sbuf, sdense, W2l, W2r, b2, flags, n_nodes);
    k_l2g<<<nblk_g, 256, 0, stream>>>(gbuf, h, sbuf, sdense, cnt, csr, ovf, ovfn, flags, d_out, n_nodes);
}